// Round 5
// baseline (746.987 us; speedup 1.0000x reference)
//
#include <hip/hip_runtime.h>
#include <hip/hip_bf16.h>

typedef __hip_bfloat16 bf16;
typedef unsigned short ush;
typedef __attribute__((ext_vector_type(8))) unsigned short ush8;
typedef __attribute__((ext_vector_type(4))) float f4;

#define IN_CH 32
#define HID 128
#define OUT_CH 32
#define S_CAP 32             // fixed csr slots per node; rank>=S_CAP -> overflow list
#define OVF_CAP 80000        // overflow pair capacity (bench data: ~0 used)
#define NB_MAX 8192          // max buckets (128 nodes each) for bucketed partition

__device__ __forceinline__ float bf2f(ush u) {
    return __uint_as_float(((unsigned)u) << 16);
}
__device__ __forceinline__ ush f2bf(float f) {
    __hip_bfloat16 b = __float2bfloat16(f);
    return __builtin_bit_cast(ush, b);
}
__device__ __forceinline__ float ldf(const void* __restrict__ p, size_t idx, int isbf16) {
    return isbf16 ? bf2f(((const ush*)p)[idx]) : ((const float*)p)[idx];
}
__device__ __forceinline__ int ld_edge(const int* __restrict__ ei, size_t elem, int wide) {
    return wide ? ei[2 * elem] : ei[elem];
}

// ---------- sniff dtypes: flags[0]=float_is_bf16, flags[1]=edge_is_i64 ----------
__global__ void k_detect(const unsigned short* __restrict__ xraw,
                         const int* __restrict__ ei, int* __restrict__ flags) {
    __shared__ int cnt_exp, any_nz;
    if (threadIdx.x == 0) { cnt_exp = 0; any_nz = 0; }
    __syncthreads();
    int local = 0;
    for (int k = threadIdx.x; k < 4096; k += 256) {
        int e = (xraw[k] >> 7) & 0xFF;
        if (e >= 100 && e <= 140) ++local;
    }
    atomicAdd(&cnt_exp, local);
    for (int k = threadIdx.x; k < 2048; k += 256)
        if (ei[2 * k + 1] != 0) any_nz = 1;   // benign race
    __syncthreads();
    if (threadIdx.x == 0) {
        flags[0] = (cnt_exp > 3500) ? 1 : 0;
        flags[1] = any_nz ? 0 : 1;
    }
}

// ---------- FALLBACK: fused count+place (one global atomic + scattered store per edge) ----------
__global__ void k_fillp(const int* __restrict__ ei, int n_edges,
                        const int* __restrict__ flags,
                        int* __restrict__ cnt, int* __restrict__ csr,
                        int* __restrict__ ovf, int* __restrict__ ovfn) {
    int e = blockIdx.x * blockDim.x + threadIdx.x;
    if (e >= n_edges) return;
    int w = flags[1];
    int d  = ld_edge(ei, (size_t)n_edges + e, w);
    int sc = ld_edge(ei, (size_t)e, w);
    int r = atomicAdd(&cnt[d], 1);
    if (r < S_CAP) {
        csr[d * S_CAP + r] = sc;
    } else {
        int o = atomicAdd(ovfn, 1);
        if (o < OVF_CAP) { ((int2*)ovf)[o] = make_int2(d, sc); }
    }
}

// ---------- bucketed partition: hist -> scan -> scatter(packed) -> build(LDS) ----------
// bucket b = dst >> 7 (128 nodes/bucket); packed record = src | (dst&127)<<25

__global__ __launch_bounds__(256) void k_hist(
        const int* __restrict__ ei, int n_edges,
        const int* __restrict__ flags,
        int* __restrict__ hist, int NB) {
    __shared__ int hl[NB_MAX];   // 32 KB
    int t = threadIdx.x;
    for (int k = t; k < NB; k += 256) hl[k] = 0;
    __syncthreads();
    int w = flags[1];
    int stride = gridDim.x * 256;
    for (int e = blockIdx.x * 256 + t; e < n_edges; e += stride) {
        int d = ld_edge(ei, (size_t)n_edges + e, w);
        atomicAdd(&hl[d >> 7], 1);
    }
    __syncthreads();
    for (int k = t; k < NB; k += 256)
        if (hl[k]) atomicAdd(&hist[k], hl[k]);
}

// single block; exclusive prefix over NB buckets; cursor[b]=base[b]
__global__ __launch_bounds__(256) void k_scan(
        const int* __restrict__ hist,
        int* __restrict__ base, int* __restrict__ cursor, int NB) {
    __shared__ int part[256];
    int t = threadIdx.x;
    int chunk = (NB + 255) / 256;
    int lo = t * chunk, hi = min(NB, (t + 1) * chunk);
    int s = 0;
    for (int k = lo; k < hi; ++k) s += hist[k];
    part[t] = s;
    __syncthreads();
    if (t == 0) {
        int r = 0;
        for (int q = 0; q < 256; ++q) { int v = part[q]; part[q] = r; r += v; }
        base[NB] = r;
    }
    __syncthreads();
    int r = part[t];
    for (int k = lo; k < hi; ++k) {
        base[k] = r; cursor[k] = r;
        r += hist[k];
    }
}

__global__ __launch_bounds__(256) void k_scatter(
        const int* __restrict__ ei, int n_edges,
        const int* __restrict__ flags,
        int* __restrict__ cursor, int* __restrict__ pairs) {
    int w = flags[1];
    int stride = gridDim.x * 256;
    for (int e = blockIdx.x * 256 + threadIdx.x; e < n_edges; e += stride) {
        int d  = ld_edge(ei, (size_t)n_edges + e, w);
        int sc = ld_edge(ei, (size_t)e, w);
        int b = d >> 7;
        int pos = atomicAdd(&cursor[b], 1);
        pairs[pos] = sc | ((d & 127) << 25);
    }
}

// one block per bucket: LDS count+place, coalesced writeout of cnt + csr image
__global__ __launch_bounds__(256) void k_build(
        const int* __restrict__ pairs, const int* __restrict__ base,
        int* __restrict__ cnt, int* __restrict__ csr,
        int* __restrict__ ovf, int* __restrict__ ovfn, int n_nodes) {
    __shared__ int cntL[128];
    __shared__ int im[128 * S_CAP];   // 16 KB
    int b = blockIdx.x;
    int t = threadIdx.x;
    for (int k = t; k < 128; k += 256) cntL[k] = 0;
    __syncthreads();
    int s0 = base[b], s1 = base[b + 1];
    int node0 = b << 7;
    for (int k = s0 + t; k < s1; k += 256) {
        int v = pairs[k];
        int src = v & 0x01FFFFFF;
        int ld = ((unsigned)v) >> 25;
        int r = atomicAdd(&cntL[ld], 1);
        if (r < S_CAP) {
            im[ld * S_CAP + r] = src;
        } else {
            int o = atomicAdd(ovfn, 1);
            if (o < OVF_CAP) { ((int2*)ovf)[o] = make_int2(node0 + ld, src); }
        }
    }
    __syncthreads();
    int nvalid = min(128, n_nodes - node0);
    for (int k = t; k < nvalid; k += 256) cnt[node0 + k] = cntL[k];
    // slack im entries (slots >= cntL) are garbage — downstream masks by lim, never dereferenced
    for (int k = t; k < nvalid * S_CAP; k += 256)
        csr[(size_t)node0 * S_CAP + k] = im[k];
}

// ==== k_agg1: agg[i][0..31] = mean_j x[j] — gather only, DUAL-node per wave ====
// lane = (slot 0..15 = edge slot, chunk 0..3 = 8-channel chunk); nodes (i, i+1) per wave
// __launch_bounds__(256,8): force VGPR<=64 -> 32 waves/CU (gather is latency-bound)
// agg stored f32 (aggf) if workspace allows, else bf16 (aggb, aliases gbuf region)
__global__ __launch_bounds__(256, 8) void k_agg1(
        const void* __restrict__ x,
        const int* __restrict__ cnt, const int* __restrict__ csr,
        const int* __restrict__ ovf, const int* __restrict__ ovfn,
        const int* __restrict__ flags,
        float* __restrict__ aggf, ush* __restrict__ aggb, int aggf32,
        int n_nodes) {
    int fb = flags[0];
    int t = threadIdx.x;
    int wave = t >> 6, lane = t & 63;
    int slot = lane >> 2;    // 0..15
    int chunk = lane & 3;    // 0..3
    int st = gridDim.x * 4 * 2;
    int i = (blockIdx.x * 4 + wave) * 2;
    if (i >= n_nodes) return;
    // prefetched csr row pair (64 ints = slots of node i and i+1) + degree pair
    int idxv = csr[(size_t)i * S_CAP + lane];
    int dgv  = cnt[min(i + (lane & 1), n_nodes - 1)];
    while (i < n_nodes) {
        int inext = i + st;
        int idxv_n = 0, dgv_n = 0;
        if (inext < n_nodes) {            // prefetch next pair (hides csr/cnt latency)
            idxv_n = csr[(size_t)inext * S_CAP + lane];
            dgv_n  = cnt[min(inext + (lane & 1), n_nodes - 1)];
        }
        int dg0 = __shfl(dgv, 0);
        int dg1 = __shfl(dgv, 1);
        bool has1 = (i + 1) < n_nodes;
        int lim0 = min(dg0, S_CAP);
        int lim1 = has1 ? min(dg1, S_CAP) : 0;
        int lmax = max(lim0, lim1);
        float acc0[8] = {0, 0, 0, 0, 0, 0, 0, 0};
        float acc1[8] = {0, 0, 0, 0, 0, 0, 0, 0};
        if (fb) {
            const ush* xb = (const ush*)x;
            for (int g = 0; g < lmax; g += 16) {
                int k = g + slot;
                int s0 = __shfl(idxv, k);
                int s1 = __shfl(idxv, 32 + k);
                bool ok0 = k < lim0;
                bool ok1 = k < lim1;
                ush8 v0 = *(const ush8*)(xb + (size_t)(ok0 ? s0 : i) * IN_CH + chunk * 8);
                ush8 v1 = *(const ush8*)(xb + (size_t)(ok1 ? s1 : i) * IN_CH + chunk * 8);
#pragma unroll
                for (int j = 0; j < 8; ++j) {
                    acc0[j] += ok0 ? bf2f(v0[j]) : 0.0f;
                    acc1[j] += ok1 ? bf2f(v1[j]) : 0.0f;
                }
            }
            if (dg0 > S_CAP) {   // wave-uniform; ~never taken
                int on = min(*ovfn, OVF_CAP);
                for (int k = 0; k < on; ++k) {
                    int2 pr = ((const int2*)ovf)[k];
                    if (pr.x == i && slot == 0) {
                        ush8 v = *(const ush8*)(xb + (size_t)pr.y * IN_CH + chunk * 8);
#pragma unroll
                        for (int j = 0; j < 8; ++j) acc0[j] += bf2f(v[j]);
                    }
                }
            }
            if (has1 && dg1 > S_CAP) {
                int on = min(*ovfn, OVF_CAP);
                for (int k = 0; k < on; ++k) {
                    int2 pr = ((const int2*)ovf)[k];
                    if (pr.x == i + 1 && slot == 0) {
                        ush8 v = *(const ush8*)(xb + (size_t)pr.y * IN_CH + chunk * 8);
#pragma unroll
                        for (int j = 0; j < 8; ++j) acc1[j] += bf2f(v[j]);
                    }
                }
            }
        } else {
            const float* xb = (const float*)x;
            for (int g = 0; g < lmax; g += 16) {
                int k = g + slot;
                int s0 = __shfl(idxv, k);
                int s1 = __shfl(idxv, 32 + k);
                bool ok0 = k < lim0;
                bool ok1 = k < lim1;
                const float* r0 = xb + (size_t)(ok0 ? s0 : i) * IN_CH + chunk * 8;
                const float* r1 = xb + (size_t)(ok1 ? s1 : i) * IN_CH + chunk * 8;
                f4 a0 = *(const f4*)r0;
                f4 a1 = *(const f4*)(r0 + 4);
                f4 b0 = *(const f4*)r1;
                f4 b1 = *(const f4*)(r1 + 4);
#pragma unroll
                for (int j = 0; j < 4; ++j) {
                    acc0[j]     += ok0 ? a0[j] : 0.0f;
                    acc0[4 + j] += ok0 ? a1[j] : 0.0f;
                    acc1[j]     += ok1 ? b0[j] : 0.0f;
                    acc1[4 + j] += ok1 ? b1[j] : 0.0f;
                }
            }
            if (dg0 > S_CAP) {
                int on = min(*ovfn, OVF_CAP);
                for (int k = 0; k < on; ++k) {
                    int2 pr = ((const int2*)ovf)[k];
                    if (pr.x == i && slot == 0) {
                        const float* rp = xb + (size_t)pr.y * IN_CH + chunk * 8;
                        f4 a0 = *(const f4*)rp;
                        f4 a1 = *(const f4*)(rp + 4);
#pragma unroll
                        for (int j = 0; j < 4; ++j) { acc0[j] += a0[j]; acc0[4 + j] += a1[j]; }
                    }
                }
            }
            if (has1 && dg1 > S_CAP) {
                int on = min(*ovfn, OVF_CAP);
                for (int k = 0; k < on; ++k) {
                    int2 pr = ((const int2*)ovf)[k];
                    if (pr.x == i + 1 && slot == 0) {
                        const float* rp = xb + (size_t)pr.y * IN_CH + chunk * 8;
                        f4 a0 = *(const f4*)rp;
                        f4 a1 = *(const f4*)(rp + 4);
#pragma unroll
                        for (int j = 0; j < 4; ++j) { acc1[j] += a0[j]; acc1[4 + j] += a1[j]; }
                    }
                }
            }
        }
#pragma unroll
        for (int j = 0; j < 8; ++j) {
            acc0[j] += __shfl_xor(acc0[j], 4);
            acc0[j] += __shfl_xor(acc0[j], 8);
            acc0[j] += __shfl_xor(acc0[j], 16);
            acc0[j] += __shfl_xor(acc0[j], 32);
            acc1[j] += __shfl_xor(acc1[j], 4);
            acc1[j] += __shfl_xor(acc1[j], 8);
            acc1[j] += __shfl_xor(acc1[j], 16);
            acc1[j] += __shfl_xor(acc1[j], 32);
        }
        if (lane < 8) {   // lanes 0..3: node i chunks 0..3; lanes 4..7: node i+1
            bool second = lane >= 4;
            if (!second || has1) {
                int node = second ? i + 1 : i;
                int dg = second ? dg1 : dg0;
                float rd = 1.0f / (float)(dg > 1 ? dg : 1);
                int c = lane & 3;
                float o[8];
#pragma unroll
                for (int j = 0; j < 8; ++j)
                    o[j] = (second ? acc1[j] : acc0[j]) * rd;
                if (aggf32) {
                    float* op = aggf + (size_t)node * IN_CH + c * 8;
                    f4 o0, o1;
#pragma unroll
                    for (int j = 0; j < 4; ++j) { o0[j] = o[j]; o1[j] = o[4 + j]; }
                    *(f4*)op = o0;
                    *(f4*)(op + 4) = o1;
                } else {
                    ush8 ov;
#pragma unroll
                    for (int j = 0; j < 8; ++j) ov[j] = f2bf(o[j]);
                    *(ush8*)(aggb + (size_t)node * IN_CH + c * 8) = ov;
                }
            }
        }
        i = inext; idxv = idxv_n; dgv = dgv_n;
    }
}

// ==== k_mm1: h[i] = relu(agg[i]@W1l^T + x[i]@W1r^T + b1), dense streaming ====
// wave-per-node; lane = (slot 0..15 = 8-output group, chunk 0..3 = 8-ch chunk)
__global__ __launch_bounds__(256) void k_mm1(
        const void* __restrict__ x,
        const float* __restrict__ aggf, const ush* __restrict__ aggb, int aggf32,
        const void* __restrict__ W1l, const void* __restrict__ W1r,
        const void* __restrict__ b1,
        const int* __restrict__ flags,
        ush* __restrict__ hout, int n_nodes) {
    __shared__ ush wst[2 * HID * IN_CH];   // 16 KB: W1l then W1r, bf16 [o][c]
    int fb = flags[0];
    int t = threadIdx.x;
    for (int idx = t; idx < HID * IN_CH; idx += 256) {
        wst[idx]                 = f2bf(ldf(W1l, idx, fb));
        wst[HID * IN_CH + idx]   = f2bf(ldf(W1r, idx, fb));
    }
    __syncthreads();
    int wave = t >> 6, lane = t & 63;
    int slot = lane >> 2;    // 0..15
    int chunk = lane & 3;    // 0..3
    ush8 wlr[8], wrr[8];
    float bsr[8];
#pragma unroll
    for (int j = 0; j < 8; ++j) {
        int o = slot * 8 + j;
        wlr[j] = *(const ush8*)&wst[o * IN_CH + chunk * 8];
        wrr[j] = *(const ush8*)&wst[HID * IN_CH + o * IN_CH + chunk * 8];
        bsr[j] = ldf(b1, o, fb);
    }
    int gw = blockIdx.x * 4 + wave;
    int nw = gridDim.x * 4;
    for (int i = gw; i < n_nodes; i += nw) {
        float acc[8], sv[8];
        if (aggf32) {
            const float* ap = aggf + (size_t)i * IN_CH + chunk * 8;
            f4 g0 = *(const f4*)ap;
            f4 g1 = *(const f4*)(ap + 4);
#pragma unroll
            for (int j = 0; j < 4; ++j) { acc[j] = g0[j]; acc[4 + j] = g1[j]; }
        } else {
            ush8 av = *(const ush8*)(aggb + (size_t)i * IN_CH + chunk * 8);
#pragma unroll
            for (int j = 0; j < 8; ++j) acc[j] = bf2f(av[j]);
        }
        if (fb) {
            ush8 svv = *(const ush8*)((const ush*)x + (size_t)i * IN_CH + chunk * 8);
#pragma unroll
            for (int j = 0; j < 8; ++j) sv[j] = bf2f(svv[j]);
        } else {
            const float* rp = (const float*)x + (size_t)i * IN_CH + chunk * 8;
            f4 a0 = *(const f4*)rp;
            f4 a1 = *(const f4*)(rp + 4);
#pragma unroll
            for (int j = 0; j < 4; ++j) { sv[j] = a0[j]; sv[4 + j] = a1[j]; }
        }
        float po[8];
#pragma unroll
        for (int j = 0; j < 8; ++j) {
            float s = 0.0f;
#pragma unroll
            for (int c = 0; c < 8; ++c)
                s += acc[c] * bf2f(wlr[j][c]) + sv[c] * bf2f(wrr[j][c]);
            po[j] = s;
        }
#pragma unroll
        for (int j = 0; j < 8; ++j) {
            po[j] += __shfl_xor(po[j], 1);
            po[j] += __shfl_xor(po[j], 2);
        }
        if (chunk == 0) {
            ush8 ov;
#pragma unroll
            for (int j = 0; j < 8; ++j) {
                float v = po[j] + bsr[j];
                ov[j] = f2bf(v > 0.0f ? v : 0.0f);
            }
            *(ush8*)(hout + (size_t)i * HID + slot * 8) = ov;
        }
    }
}

// ==== k_g: g -> DENSE gbuf[N][32]; s -> h row [32..63] ====
__global__ __launch_bounds__(256) void k_g(
        ush* __restrict__ h, ush* __restrict__ gout,
        const void* __restrict__ W2l, const void* __restrict__ W2r,
        const void* __restrict__ b2,
        const int* __restrict__ flags, int n_nodes) {
    __shared__ ush wst[2 * OUT_CH * HID];  // 16 KB
    int fb = flags[0];
    int t = threadIdx.x;
    for (int idx = t; idx < OUT_CH * HID; idx += 256) {
        wst[idx]                  = f2bf(ldf(W2l, idx, fb));
        wst[OUT_CH * HID + idx]   = f2bf(ldf(W2r, idx, fb));
    }
    __syncthreads();
    int wave = t >> 6, lane = t & 63;
    int slot = lane >> 4;    // 0..3
    int chunk = lane & 15;   // 0..15
    ush8 wlr[8], wrr[8];
    float bsr[8];
#pragma unroll
    for (int j = 0; j < 8; ++j) {
        int o = slot * 8 + j;
        wlr[j] = *(const ush8*)&wst[o * HID + chunk * 8];
        wrr[j] = *(const ush8*)&wst[OUT_CH * HID + o * HID + chunk * 8];
        bsr[j] = ldf(b2, o, fb);
    }
    int gw = blockIdx.x * 4 + wave;
    int nw = gridDim.x * 4;
    for (int i = gw; i < n_nodes; i += nw) {
        ush8 hv = *(const ush8*)(h + (size_t)i * HID + chunk * 8);  // read BEFORE write
        float sv[8];
#pragma unroll
        for (int j = 0; j < 8; ++j) sv[j] = bf2f(hv[j]);
        float pg[8], ps[8];
#pragma unroll
        for (int j = 0; j < 8; ++j) {
            float a = 0.0f, b = 0.0f;
#pragma unroll
            for (int c = 0; c < 8; ++c) {
                a += sv[c] * bf2f(wlr[j][c]);
                b += sv[c] * bf2f(wrr[j][c]);
            }
            pg[j] = a; ps[j] = b;
        }
#pragma unroll
        for (int j = 0; j < 8; ++j) {
            pg[j] += __shfl_xor(pg[j], 1);
            pg[j] += __shfl_xor(pg[j], 2);
            pg[j] += __shfl_xor(pg[j], 4);
            pg[j] += __shfl_xor(pg[j], 8);
            ps[j] += __shfl_xor(ps[j], 1);
            ps[j] += __shfl_xor(ps[j], 2);
            ps[j] += __shfl_xor(ps[j], 4);
            ps[j] += __shfl_xor(ps[j], 8);
        }
        if (chunk == 0) {
            ush8 go, so;
#pragma unroll
            for (int j = 0; j < 8; ++j) {
                go[j] = f2bf(pg[j]);
                so[j] = f2bf(ps[j] + bsr[j]);
            }
            *(ush8*)(gout + (size_t)i * OUT_CH + slot * 8)    = go;   // g -> dense [N][32]
            *(ush8*)(h + (size_t)i * HID + 32 + slot * 8)     = so;   // s -> h row [32..63]
        }
    }
}

// ==== k_l2g: out[i] = mean_j g[j] + s[i] — DUAL-node gather from dense gbuf ====
__global__ __launch_bounds__(256, 8) void k_l2g(
        const ush* __restrict__ gbuf, const ush* __restrict__ hs,
        const int* __restrict__ cnt, const int* __restrict__ csr,
        const int* __restrict__ ovf, const int* __restrict__ ovfn,
        const int* __restrict__ flags,
        void* __restrict__ out, int n_nodes) {
    int fb = flags[0];
    int t = threadIdx.x;
    int wave = t >> 6, lane = t & 63;
    int slot = lane >> 2;    // 0..15
    int chunk = lane & 3;    // 0..3
    int st = gridDim.x * 4 * 2;
    int i = (blockIdx.x * 4 + wave) * 2;
    if (i >= n_nodes) return;
    int idxv = csr[(size_t)i * S_CAP + lane];
    int dgv  = cnt[min(i + (lane & 1), n_nodes - 1)];
    while (i < n_nodes) {
        int inext = i + st;
        int idxv_n = 0, dgv_n = 0;
        if (inext < n_nodes) {
            idxv_n = csr[(size_t)inext * S_CAP + lane];
            dgv_n  = cnt[min(inext + (lane & 1), n_nodes - 1)];
        }
        int dg0 = __shfl(dgv, 0);
        int dg1 = __shfl(dgv, 1);
        bool has1 = (i + 1) < n_nodes;
        int lim0 = min(dg0, S_CAP);
        int lim1 = has1 ? min(dg1, S_CAP) : 0;
        int lmax = max(lim0, lim1);
        float acc0[8] = {0, 0, 0, 0, 0, 0, 0, 0};
        float acc1[8] = {0, 0, 0, 0, 0, 0, 0, 0};
        for (int g = 0; g < lmax; g += 16) {
            int k = g + slot;
            int s0 = __shfl(idxv, k);
            int s1 = __shfl(idxv, 32 + k);
            bool ok0 = k < lim0;
            bool ok1 = k < lim1;
            ush8 v0 = *(const ush8*)(gbuf + (size_t)(ok0 ? s0 : i) * OUT_CH + chunk * 8);
            ush8 v1 = *(const ush8*)(gbuf + (size_t)(ok1 ? s1 : i) * OUT_CH + chunk * 8);
#pragma unroll
            for (int j = 0; j < 8; ++j) {
                acc0[j] += ok0 ? bf2f(v0[j]) : 0.0f;
                acc1[j] += ok1 ? bf2f(v1[j]) : 0.0f;
            }
        }
        if (dg0 > S_CAP) {   // wave-uniform; ~never taken
            int on = min(*ovfn, OVF_CAP);
            for (int k = 0; k < on; ++k) {
                int2 pr = ((const int2*)ovf)[k];
                if (pr.x == i && slot == 0) {
                    ush8 v = *(const ush8*)(gbuf + (size_t)pr.y * OUT_CH + chunk * 8);
#pragma unroll
                    for (int j = 0; j < 8; ++j) acc0[j] += bf2f(v[j]);
                }
            }
        }
        if (has1 && dg1 > S_CAP) {
            int on = min(*ovfn, OVF_CAP);
            for (int k = 0; k < on; ++k) {
                int2 pr = ((const int2*)ovf)[k];
                if (pr.x == i + 1 && slot == 0) {
                    ush8 v = *(const ush8*)(gbuf + (size_t)pr.y * OUT_CH + chunk * 8);
#pragma unroll
                    for (int j = 0; j < 8; ++j) acc1[j] += bf2f(v[j]);
                }
            }
        }
#pragma unroll
        for (int j = 0; j < 8; ++j) {
            acc0[j] += __shfl_xor(acc0[j], 4);
            acc0[j] += __shfl_xor(acc0[j], 8);
            acc0[j] += __shfl_xor(acc0[j], 16);
            acc0[j] += __shfl_xor(acc0[j], 32);
            acc1[j] += __shfl_xor(acc1[j], 4);
            acc1[j] += __shfl_xor(acc1[j], 8);
            acc1[j] += __shfl_xor(acc1[j], 16);
            acc1[j] += __shfl_xor(acc1[j], 32);
        }
        if (lane < 8) {   // lanes 0..3: node i; lanes 4..7: node i+1
            bool second = lane >= 4;
            if (!second || has1) {
                int node = second ? i + 1 : i;
                int dg = second ? dg1 : dg0;
                float rd = 1.0f / (float)(dg > 1 ? dg : 1);
                int c = lane & 3;
                ush8 selfv = *(const ush8*)(hs + (size_t)node * HID + 32 + c * 8);
                if (fb) {
                    ush8 ov;
#pragma unroll
                    for (int j = 0; j < 8; ++j) {
                        float a = second ? acc1[j] : acc0[j];
                        ov[j] = f2bf(a * rd + bf2f(selfv[j]));
                    }
                    *(ush8*)((ush*)out + (size_t)node * OUT_CH + c * 8) = ov;
                } else {
                    float* op = (float*)out + (size_t)node * OUT_CH + c * 8;
                    f4 a0, a1;
#pragma unroll
                    for (int j = 0; j < 4; ++j) {
                        float x0 = second ? acc1[j]     : acc0[j];
                        float x1 = second ? acc1[4 + j] : acc0[4 + j];
                        a0[j] = x0 * rd + bf2f(selfv[j]);
                        a1[j] = x1 * rd + bf2f(selfv[4 + j]);
                    }
                    *(f4*)op = a0;
                    *(f4*)(op + 4) = a1;
                }
            }
        }
        i = inext; idxv = idxv_n; dgv = dgv_n;
    }
}

extern "C" void kernel_launch(void* const* d_in, const int* in_sizes, int n_in,
                              void* d_out, int out_size, void* d_ws, size_t ws_size,
                              hipStream_t stream) {
    const void* x   = d_in[0];
    const int*  ei  = (const int*)d_in[1];
    const void* W1l = d_in[2];
    const void* W1r = d_in[3];
    const void* b1  = d_in[4];
    const void* W2l = d_in[5];
    const void* W2r = d_in[6];
    const void* b2  = d_in[7];

    int n_nodes = in_sizes[0] / IN_CH;
    int n_edges = in_sizes[1] / 2;

    // ws layout:
    //   [0,256)   flags (2 ints) + ovfn counter (at +128)
    //   cnt (N ints) | csr (N*S_CAP + 64 ints)
    //   | ovf region (OVF_CAP pairs = 640KB), then hist/base/cursor carve:
    //     hist NB_MAX + base NB_MAX+1 + curs NB_MAX ints = 3*NB_MAX+1 ints (~96KB)
    //     [ROUND-4 BUG: carve was 2*(NB_MAX+2) ints = 64KB -> curs overlapped pairs
    //      -> k_scatter cursor corruption -> OOB store -> core dump. Fixed: 3*(NB_MAX+2).]
    //   | h (N*HID bf16)   -- pairs[] for bucketed partition ALIASES h (dead until k_mm1)
    //   | gbuf (N*OUT_CH bf16)
    //   | agg (N*IN_CH f32)  -- only if ws_size permits; else bf16 aliased onto gbuf
    char* ws = (char*)d_ws;
    size_t o_cnt = 256;
    size_t o_csr = (o_cnt + (size_t)n_nodes * 4 + 127) & ~(size_t)127;
    size_t o_ovf = (o_csr + ((size_t)n_nodes * S_CAP + 64) * 4 + 127) & ~(size_t)127;
    size_t o_hist = o_ovf + (size_t)OVF_CAP * 8;           // ~96KB carve after ovf pairs
    size_t o_h   = (o_hist + (size_t)(3 * (NB_MAX + 2)) * 4 + 255) & ~(size_t)255;
    size_t o_gb  = (o_h + (size_t)n_nodes * HID * 2 + 255) & ~(size_t)255;
    size_t o_ag  = (o_gb + (size_t)n_nodes * OUT_CH * 2 + 255) & ~(size_t)255;
    size_t need_f32 = o_ag + (size_t)n_nodes * IN_CH * 4;

    int* flags = (int*)ws;
    int* ovfn  = (int*)(ws + 128);
    int* cnt   = (int*)(ws + o_cnt);
    int* csr   = (int*)(ws + o_csr);
    int* ovf   = (int*)(ws + o_ovf);
    int* hist  = (int*)(ws + o_hist);              // NB_MAX ints
    int* base  = hist + NB_MAX;                    // NB_MAX+1 ints
    int* curs  = base + NB_MAX + 1;                // NB_MAX ints
    ush* h     = (ush*)(ws + o_h);
    int* pairs = (int*)(ws + o_h);                 // aliases h; dead before k_mm1
    ush* gbuf  = (ush*)(ws + o_gb);

    int aggf32 = (ws_size >= need_f32) ? 1 : 0;
    float* aggf = (float*)(ws + o_ag);   // valid only if aggf32
    ush*   aggb = gbuf;                  // bf16 fallback aliases gbuf (safe: dead by k_g)

    int NB = (n_nodes + 127) >> 7;
    // bucketed path requires: NB fits LDS hist; src fits 25 bits; pairs fits in h region
    int use_bucket = (NB <= NB_MAX) && (n_nodes < (1 << 25)) &&
                     ((size_t)n_edges * 4 <= (size_t)n_nodes * HID * 2) && (n_edges > 0);

    hipMemsetAsync(ws, 0, 256, stream);                          // flags + ovfn

    k_detect<<<1, 256, 0, stream>>>((const unsigned short*)x, ei, flags);

    if (use_bucket) {
        hipMemsetAsync(hist, 0, (size_t)NB * 4, stream);
        k_hist<<<256, 256, 0, stream>>>(ei, n_edges, flags, hist, NB);
        k_scan<<<1, 256, 0, stream>>>(hist, base, curs, NB);
        k_scatter<<<2048, 256, 0, stream>>>(ei, n_edges, flags, curs, pairs);
        k_build<<<NB, 256, 0, stream>>>(pairs, base, cnt, csr, ovf, ovfn, n_nodes);
    } else {
        hipMemsetAsync(cnt, 0, (size_t)n_nodes * 4, stream);
        k_fillp<<<(n_edges + 255) / 256, 256, 0, stream>>>(ei, n_edges, flags, cnt, csr, ovf, ovfn);
    }

    // gather kernels: lean VGPR (<=64) -> 32 waves/CU; 2048 blocks = 8/CU residency cap
    k_agg1<<<2048, 256, 0, stream>>>(x, cnt, csr, ovf, ovfn, flags, aggf, aggb, aggf32, n_nodes);
    // dense kernels: ~104 VGPR -> 4 blocks/CU cap; 1024 blocks exactly fills it
    k_mm1<<<1024, 256, 0, stream>>>(x, aggf, aggb, aggf32, W1l, W1r, b1, flags, h, n_nodes);
    k_g<<<1024, 256, 0, stream>>>(h, gbuf, W2l, W2r, b2, flags, n_nodes);
    k_l2g<<<2048, 256, 0, stream>>>(gbuf, h, cnt, csr, ovf, ovfn, flags, d_out, n_nodes);
}

// Round 6
// 395.163 us; speedup vs baseline: 1.8903x; 1.8903x over previous
//
#include <hip/hip_runtime.h>
#include <hip/hip_bf16.h>

typedef __hip_bfloat16 bf16;
typedef unsigned short ush;
typedef __attribute__((ext_vector_type(8))) unsigned short ush8;
typedef __attribute__((ext_vector_type(4))) float f4;

#define IN_CH 32
#define HID 128
#define OUT_CH 32
#define S_CAP 32             // fixed csr slots per node; rank>=S_CAP -> overflow list
#define OVF_CAP 80000        // overflow pair capacity (bench data: ~0 used)
#define NB_MAX 2048          // max buckets (256 nodes each) -> n_nodes <= 524288
#define SC_CHUNK 8192        // edges per block in chunked scatter

__device__ __forceinline__ float bf2f(ush u) {
    return __uint_as_float(((unsigned)u) << 16);
}
__device__ __forceinline__ ush f2bf(float f) {
    __hip_bfloat16 b = __float2bfloat16(f);
    return __builtin_bit_cast(ush, b);
}
__device__ __forceinline__ float ldf(const void* __restrict__ p, size_t idx, int isbf16) {
    return isbf16 ? bf2f(((const ush*)p)[idx]) : ((const float*)p)[idx];
}
__device__ __forceinline__ int ld_edge(const int* __restrict__ ei, size_t elem, int wide) {
    return wide ? ei[2 * elem] : ei[elem];
}

// ---------- sniff dtypes: flags[0]=float_is_bf16, flags[1]=edge_is_i64 ----------
__global__ void k_detect(const unsigned short* __restrict__ xraw,
                         const int* __restrict__ ei, int* __restrict__ flags) {
    __shared__ int cnt_exp, any_nz;
    if (threadIdx.x == 0) { cnt_exp = 0; any_nz = 0; }
    __syncthreads();
    int local = 0;
    for (int k = threadIdx.x; k < 4096; k += 256) {
        int e = (xraw[k] >> 7) & 0xFF;
        if (e >= 100 && e <= 140) ++local;
    }
    atomicAdd(&cnt_exp, local);
    for (int k = threadIdx.x; k < 2048; k += 256)
        if (ei[2 * k + 1] != 0) any_nz = 1;   // benign race
    __syncthreads();
    if (threadIdx.x == 0) {
        flags[0] = (cnt_exp > 3500) ? 1 : 0;
        flags[1] = any_nz ? 0 : 1;
    }
}

// ---------- FALLBACK: fused count+place (one global atomic + scattered store per edge) ----------
__global__ void k_fillp(const int* __restrict__ ei, int n_edges,
                        const int* __restrict__ flags,
                        int* __restrict__ cnt, int* __restrict__ csr,
                        int* __restrict__ ovf, int* __restrict__ ovfn) {
    int e = blockIdx.x * blockDim.x + threadIdx.x;
    if (e >= n_edges) return;
    int w = flags[1];
    int d  = ld_edge(ei, (size_t)n_edges + e, w);
    int sc = ld_edge(ei, (size_t)e, w);
    int r = atomicAdd(&cnt[d], 1);
    if (r < S_CAP) {
        csr[d * S_CAP + r] = sc;
    } else {
        int o = atomicAdd(ovfn, 1);
        if (o < OVF_CAP) { ((int2*)ovf)[o] = make_int2(d, sc); }
    }
}

// ---------- bucketed partition: hist -> scan -> chunked scatter -> build(LDS) ----------
// bucket b = dst >> 8 (256 nodes/bucket); packed record = src | (dst&255)<<24

__global__ __launch_bounds__(256) void k_hist(
        const int* __restrict__ ei, int n_edges,
        const int* __restrict__ flags,
        int* __restrict__ hist, int NB) {
    __shared__ int hl[NB_MAX];   // 8 KB
    int t = threadIdx.x;
    for (int k = t; k < NB; k += 256) hl[k] = 0;
    __syncthreads();
    int w = flags[1];
    int stride = gridDim.x * 256;
    for (int e = blockIdx.x * 256 + t; e < n_edges; e += stride) {
        int d = ld_edge(ei, (size_t)n_edges + e, w);
        atomicAdd(&hl[d >> 8], 1);
    }
    __syncthreads();
    for (int k = t; k < NB; k += 256)
        if (hl[k]) atomicAdd(&hist[k], hl[k]);
}

// single block; exclusive prefix over NB buckets; cursor[b]=base[b]
__global__ __launch_bounds__(256) void k_scan(
        const int* __restrict__ hist,
        int* __restrict__ base, int* __restrict__ cursor, int NB) {
    __shared__ int part[256];
    int t = threadIdx.x;
    int chunk = (NB + 255) / 256;
    int lo = t * chunk, hi = min(NB, (t + 1) * chunk);
    int s = 0;
    for (int k = lo; k < hi; ++k) s += hist[k];
    part[t] = s;
    __syncthreads();
    if (t == 0) {
        int r = 0;
        for (int q = 0; q < 256; ++q) { int v = part[q]; part[q] = r; r += v; }
        base[NB] = r;
    }
    __syncthreads();
    int r = part[t];
    for (int k = lo; k < hi; ++k) {
        base[k] = r; cursor[k] = r;
        r += hist[k];
    }
}

// chunked two-pass scatter: per (block,bucket) ONE global atomic reservation,
// then contiguous segment writes (fills lines -> no 64B/record amplification).
__global__ __launch_bounds__(256) void k_scatter(
        const int* __restrict__ ei, int n_edges,
        const int* __restrict__ flags,
        int* __restrict__ cursor, int* __restrict__ pairs, int NB) {
    __shared__ int cA[NB_MAX];   // pass A: chunk histogram; pass B: rank counter
    __shared__ int oA[NB_MAX];   // reserved global offset per bucket
    int t = threadIdx.x;
    int w = flags[1];
    int e0 = blockIdx.x * SC_CHUNK;
    int ecnt = min(SC_CHUNK, n_edges - e0);
    if (ecnt <= 0) return;
    for (int k = t; k < NB; k += 256) cA[k] = 0;
    __syncthreads();
    // pass A: chunk histogram (LDS atomics)
    for (int k = t; k < ecnt; k += 256) {
        int d = ld_edge(ei, (size_t)n_edges + e0 + k, w);
        atomicAdd(&cA[d >> 8], 1);
    }
    __syncthreads();
    // reserve: one global atomic per non-empty (block,bucket); reset rank counters
    for (int b = t; b < NB; b += 256) {
        int c = cA[b];
        oA[b] = c ? atomicAdd(&cursor[b], c) : 0;
        cA[b] = 0;
    }
    __syncthreads();
    // pass B: place records contiguously within reserved segments
    for (int k = t; k < ecnt; k += 256) {
        int d  = ld_edge(ei, (size_t)n_edges + e0 + k, w);
        int sc = ld_edge(ei, (size_t)e0 + k, w);
        int b = d >> 8;
        int r = atomicAdd(&cA[b], 1);
        pairs[oA[b] + r] = sc | ((d & 255) << 24);
    }
}

// one block per bucket (256 nodes): LDS count+place, coalesced writeout of cnt + csr
__global__ __launch_bounds__(256) void k_build(
        const int* __restrict__ pairs, const int* __restrict__ base,
        int* __restrict__ cnt, int* __restrict__ csr,
        int* __restrict__ ovf, int* __restrict__ ovfn, int n_nodes) {
    __shared__ int cntL[256];
    __shared__ int im[256 * S_CAP];   // 32 KB
    int b = blockIdx.x;
    int t = threadIdx.x;
    cntL[t] = 0;
    __syncthreads();
    int s0 = base[b], s1 = base[b + 1];
    int node0 = b << 8;
    for (int k = s0 + t; k < s1; k += 256) {
        int v = pairs[k];
        int src = v & 0x00FFFFFF;
        int ld = ((unsigned)v) >> 24;
        int r = atomicAdd(&cntL[ld], 1);
        if (r < S_CAP) {
            im[ld * S_CAP + r] = src;
        } else {
            int o = atomicAdd(ovfn, 1);
            if (o < OVF_CAP) { ((int2*)ovf)[o] = make_int2(node0 + ld, src); }
        }
    }
    __syncthreads();
    int nvalid = min(256, n_nodes - node0);
    if (t < nvalid) cnt[node0 + t] = cntL[t];
    // slack im entries (slots >= cntL) are garbage — downstream masks by lim, never dereferenced
    for (int k = t; k < nvalid * S_CAP; k += 256)
        csr[(size_t)node0 * S_CAP + k] = im[k];
}

// ==== k_agg1: agg[i][0..31] = mean_j x[j] — gather only, DUAL-node per wave ====
// lane = (slot 0..15 = edge slot, chunk 0..3 = 8-channel chunk); nodes (i, i+1) per wave
// __launch_bounds__(256,8): force VGPR<=64 -> 32 waves/CU (gather is latency-bound)
// agg stored f32 (aggf) if workspace allows, else bf16 (aggb, aliases gbuf region)
__global__ __launch_bounds__(256, 8) void k_agg1(
        const void* __restrict__ x,
        const int* __restrict__ cnt, const int* __restrict__ csr,
        const int* __restrict__ ovf, const int* __restrict__ ovfn,
        const int* __restrict__ flags,
        float* __restrict__ aggf, ush* __restrict__ aggb, int aggf32,
        int n_nodes) {
    int fb = flags[0];
    int t = threadIdx.x;
    int wave = t >> 6, lane = t & 63;
    int slot = lane >> 2;    // 0..15
    int chunk = lane & 3;    // 0..3
    int st = gridDim.x * 4 * 2;
    int i = (blockIdx.x * 4 + wave) * 2;
    if (i >= n_nodes) return;
    // prefetched csr row pair (64 ints = slots of node i and i+1) + degree pair
    int idxv = csr[(size_t)i * S_CAP + lane];
    int dgv  = cnt[min(i + (lane & 1), n_nodes - 1)];
    while (i < n_nodes) {
        int inext = i + st;
        int idxv_n = 0, dgv_n = 0;
        if (inext < n_nodes) {            // prefetch next pair (hides csr/cnt latency)
            idxv_n = csr[(size_t)inext * S_CAP + lane];
            dgv_n  = cnt[min(inext + (lane & 1), n_nodes - 1)];
        }
        int dg0 = __shfl(dgv, 0);
        int dg1 = __shfl(dgv, 1);
        bool has1 = (i + 1) < n_nodes;
        int lim0 = min(dg0, S_CAP);
        int lim1 = has1 ? min(dg1, S_CAP) : 0;
        int lmax = max(lim0, lim1);
        float acc0[8] = {0, 0, 0, 0, 0, 0, 0, 0};
        float acc1[8] = {0, 0, 0, 0, 0, 0, 0, 0};
        if (fb) {
            const ush* xb = (const ush*)x;
            for (int g = 0; g < lmax; g += 16) {
                int k = g + slot;
                int s0 = __shfl(idxv, k);
                int s1 = __shfl(idxv, 32 + k);
                bool ok0 = k < lim0;
                bool ok1 = k < lim1;
                ush8 v0 = *(const ush8*)(xb + (size_t)(ok0 ? s0 : i) * IN_CH + chunk * 8);
                ush8 v1 = *(const ush8*)(xb + (size_t)(ok1 ? s1 : i) * IN_CH + chunk * 8);
#pragma unroll
                for (int j = 0; j < 8; ++j) {
                    acc0[j] += ok0 ? bf2f(v0[j]) : 0.0f;
                    acc1[j] += ok1 ? bf2f(v1[j]) : 0.0f;
                }
            }
            if (dg0 > S_CAP) {   // wave-uniform; ~never taken
                int on = min(*ovfn, OVF_CAP);
                for (int k = 0; k < on; ++k) {
                    int2 pr = ((const int2*)ovf)[k];
                    if (pr.x == i && slot == 0) {
                        ush8 v = *(const ush8*)(xb + (size_t)pr.y * IN_CH + chunk * 8);
#pragma unroll
                        for (int j = 0; j < 8; ++j) acc0[j] += bf2f(v[j]);
                    }
                }
            }
            if (has1 && dg1 > S_CAP) {
                int on = min(*ovfn, OVF_CAP);
                for (int k = 0; k < on; ++k) {
                    int2 pr = ((const int2*)ovf)[k];
                    if (pr.x == i + 1 && slot == 0) {
                        ush8 v = *(const ush8*)(xb + (size_t)pr.y * IN_CH + chunk * 8);
#pragma unroll
                        for (int j = 0; j < 8; ++j) acc1[j] += bf2f(v[j]);
                    }
                }
            }
        } else {
            const float* xb = (const float*)x;
            for (int g = 0; g < lmax; g += 16) {
                int k = g + slot;
                int s0 = __shfl(idxv, k);
                int s1 = __shfl(idxv, 32 + k);
                bool ok0 = k < lim0;
                bool ok1 = k < lim1;
                const float* r0 = xb + (size_t)(ok0 ? s0 : i) * IN_CH + chunk * 8;
                const float* r1 = xb + (size_t)(ok1 ? s1 : i) * IN_CH + chunk * 8;
                f4 a0 = *(const f4*)r0;
                f4 a1 = *(const f4*)(r0 + 4);
                f4 b0 = *(const f4*)r1;
                f4 b1 = *(const f4*)(r1 + 4);
#pragma unroll
                for (int j = 0; j < 4; ++j) {
                    acc0[j]     += ok0 ? a0[j] : 0.0f;
                    acc0[4 + j] += ok0 ? a1[j] : 0.0f;
                    acc1[j]     += ok1 ? b0[j] : 0.0f;
                    acc1[4 + j] += ok1 ? b1[j] : 0.0f;
                }
            }
            if (dg0 > S_CAP) {
                int on = min(*ovfn, OVF_CAP);
                for (int k = 0; k < on; ++k) {
                    int2 pr = ((const int2*)ovf)[k];
                    if (pr.x == i && slot == 0) {
                        const float* rp = xb + (size_t)pr.y * IN_CH + chunk * 8;
                        f4 a0 = *(const f4*)rp;
                        f4 a1 = *(const f4*)(rp + 4);
#pragma unroll
                        for (int j = 0; j < 4; ++j) { acc0[j] += a0[j]; acc0[4 + j] += a1[j]; }
                    }
                }
            }
            if (has1 && dg1 > S_CAP) {
                int on = min(*ovfn, OVF_CAP);
                for (int k = 0; k < on; ++k) {
                    int2 pr = ((const int2*)ovf)[k];
                    if (pr.x == i + 1 && slot == 0) {
                        const float* rp = xb + (size_t)pr.y * IN_CH + chunk * 8;
                        f4 a0 = *(const f4*)rp;
                        f4 a1 = *(const f4*)(rp + 4);
#pragma unroll
                        for (int j = 0; j < 4; ++j) { acc1[j] += a0[j]; acc1[4 + j] += a1[j]; }
                    }
                }
            }
        }
#pragma unroll
        for (int j = 0; j < 8; ++j) {
            acc0[j] += __shfl_xor(acc0[j], 4);
            acc0[j] += __shfl_xor(acc0[j], 8);
            acc0[j] += __shfl_xor(acc0[j], 16);
            acc0[j] += __shfl_xor(acc0[j], 32);
            acc1[j] += __shfl_xor(acc1[j], 4);
            acc1[j] += __shfl_xor(acc1[j], 8);
            acc1[j] += __shfl_xor(acc1[j], 16);
            acc1[j] += __shfl_xor(acc1[j], 32);
        }
        if (lane < 8) {   // lanes 0..3: node i chunks 0..3; lanes 4..7: node i+1
            bool second = lane >= 4;
            if (!second || has1) {
                int node = second ? i + 1 : i;
                int dg = second ? dg1 : dg0;
                float rd = 1.0f / (float)(dg > 1 ? dg : 1);
                int c = lane & 3;
                float o[8];
#pragma unroll
                for (int j = 0; j < 8; ++j)
                    o[j] = (second ? acc1[j] : acc0[j]) * rd;
                if (aggf32) {
                    float* op = aggf + (size_t)node * IN_CH + c * 8;
                    f4 o0, o1;
#pragma unroll
                    for (int j = 0; j < 4; ++j) { o0[j] = o[j]; o1[j] = o[4 + j]; }
                    *(f4*)op = o0;
                    *(f4*)(op + 4) = o1;
                } else {
                    ush8 ov;
#pragma unroll
                    for (int j = 0; j < 8; ++j) ov[j] = f2bf(o[j]);
                    *(ush8*)(aggb + (size_t)node * IN_CH + c * 8) = ov;
                }
            }
        }
        i = inext; idxv = idxv_n; dgv = dgv_n;
    }
}

// ==== k_mm1: h[i] = relu(agg[i]@W1l^T + x[i]@W1r^T + b1), dense streaming ====
// wave-per-node; lane = (slot 0..15 = 8-output group, chunk 0..3 = 8-ch chunk)
__global__ __launch_bounds__(256) void k_mm1(
        const void* __restrict__ x,
        const float* __restrict__ aggf, const ush* __restrict__ aggb, int aggf32,
        const void* __restrict__ W1l, const void* __restrict__ W1r,
        const void* __restrict__ b1,
        const int* __restrict__ flags,
        ush* __restrict__ hout, int n_nodes) {
    __shared__ ush wst[2 * HID * IN_CH];   // 16 KB: W1l then W1r, bf16 [o][c]
    int fb = flags[0];
    int t = threadIdx.x;
    for (int idx = t; idx < HID * IN_CH; idx += 256) {
        wst[idx]                 = f2bf(ldf(W1l, idx, fb));
        wst[HID * IN_CH + idx]   = f2bf(ldf(W1r, idx, fb));
    }
    __syncthreads();
    int wave = t >> 6, lane = t & 63;
    int slot = lane >> 2;    // 0..15
    int chunk = lane & 3;    // 0..3
    ush8 wlr[8], wrr[8];
    float bsr[8];
#pragma unroll
    for (int j = 0; j < 8; ++j) {
        int o = slot * 8 + j;
        wlr[j] = *(const ush8*)&wst[o * IN_CH + chunk * 8];
        wrr[j] = *(const ush8*)&wst[HID * IN_CH + o * IN_CH + chunk * 8];
        bsr[j] = ldf(b1, o, fb);
    }
    int gw = blockIdx.x * 4 + wave;
    int nw = gridDim.x * 4;
    for (int i = gw; i < n_nodes; i += nw) {
        float acc[8], sv[8];
        if (aggf32) {
            const float* ap = aggf + (size_t)i * IN_CH + chunk * 8;
            f4 g0 = *(const f4*)ap;
            f4 g1 = *(const f4*)(ap + 4);
#pragma unroll
            for (int j = 0; j < 4; ++j) { acc[j] = g0[j]; acc[4 + j] = g1[j]; }
        } else {
            ush8 av = *(const ush8*)(aggb + (size_t)i * IN_CH + chunk * 8);
#pragma unroll
            for (int j = 0; j < 8; ++j) acc[j] = bf2f(av[j]);
        }
        if (fb) {
            ush8 svv = *(const ush8*)((const ush*)x + (size_t)i * IN_CH + chunk * 8);
#pragma unroll
            for (int j = 0; j < 8; ++j) sv[j] = bf2f(svv[j]);
        } else {
            const float* rp = (const float*)x + (size_t)i * IN_CH + chunk * 8;
            f4 a0 = *(const f4*)rp;
            f4 a1 = *(const f4*)(rp + 4);
#pragma unroll
            for (int j = 0; j < 4; ++j) { sv[j] = a0[j]; sv[4 + j] = a1[j]; }
        }
        float po[8];
#pragma unroll
        for (int j = 0; j < 8; ++j) {
            float s = 0.0f;
#pragma unroll
            for (int c = 0; c < 8; ++c)
                s += acc[c] * bf2f(wlr[j][c]) + sv[c] * bf2f(wrr[j][c]);
            po[j] = s;
        }
#pragma unroll
        for (int j = 0; j < 8; ++j) {
            po[j] += __shfl_xor(po[j], 1);
            po[j] += __shfl_xor(po[j], 2);
        }
        if (chunk == 0) {
            ush8 ov;
#pragma unroll
            for (int j = 0; j < 8; ++j) {
                float v = po[j] + bsr[j];
                ov[j] = f2bf(v > 0.0f ? v : 0.0f);
            }
            *(ush8*)(hout + (size_t)i * HID + slot * 8) = ov;
        }
    }
}

// ==== k_g: g -> DENSE gbuf[N][32]; s -> h row [32..63] ====
__global__ __launch_bounds__(256) void k_g(
        ush* __restrict__ h, ush* __restrict__ gout,
        const void* __restrict__ W2l, const void* __restrict__ W2r,
        const void* __restrict__ b2,
        const int* __restrict__ flags, int n_nodes) {
    __shared__ ush wst[2 * OUT_CH * HID];  // 16 KB
    int fb = flags[0];
    int t = threadIdx.x;
    for (int idx = t; idx < OUT_CH * HID; idx += 256) {
        wst[idx]                  = f2bf(ldf(W2l, idx, fb));
        wst[OUT_CH * HID + idx]   = f2bf(ldf(W2r, idx, fb));
    }
    __syncthreads();
    int wave = t >> 6, lane = t & 63;
    int slot = lane >> 4;    // 0..3
    int chunk = lane & 15;   // 0..15
    ush8 wlr[8], wrr[8];
    float bsr[8];
#pragma unroll
    for (int j = 0; j < 8; ++j) {
        int o = slot * 8 + j;
        wlr[j] = *(const ush8*)&wst[o * HID + chunk * 8];
        wrr[j] = *(const ush8*)&wst[OUT_CH * HID + o * HID + chunk * 8];
        bsr[j] = ldf(b2, o, fb);
    }
    int gw = blockIdx.x * 4 + wave;
    int nw = gridDim.x * 4;
    for (int i = gw; i < n_nodes; i += nw) {
        ush8 hv = *(const ush8*)(h + (size_t)i * HID + chunk * 8);  // read BEFORE write
        float sv[8];
#pragma unroll
        for (int j = 0; j < 8; ++j) sv[j] = bf2f(hv[j]);
        float pg[8], ps[8];
#pragma unroll
        for (int j = 0; j < 8; ++j) {
            float a = 0.0f, b = 0.0f;
#pragma unroll
            for (int c = 0; c < 8; ++c) {
                a += sv[c] * bf2f(wlr[j][c]);
                b += sv[c] * bf2f(wrr[j][c]);
            }
            pg[j] = a; ps[j] = b;
        }
#pragma unroll
        for (int j = 0; j < 8; ++j) {
            pg[j] += __shfl_xor(pg[j], 1);
            pg[j] += __shfl_xor(pg[j], 2);
            pg[j] += __shfl_xor(pg[j], 4);
            pg[j] += __shfl_xor(pg[j], 8);
            ps[j] += __shfl_xor(ps[j], 1);
            ps[j] += __shfl_xor(ps[j], 2);
            ps[j] += __shfl_xor(ps[j], 4);
            ps[j] += __shfl_xor(ps[j], 8);
        }
        if (chunk == 0) {
            ush8 go, so;
#pragma unroll
            for (int j = 0; j < 8; ++j) {
                go[j] = f2bf(pg[j]);
                so[j] = f2bf(ps[j] + bsr[j]);
            }
            *(ush8*)(gout + (size_t)i * OUT_CH + slot * 8)    = go;   // g -> dense [N][32]
            *(ush8*)(h + (size_t)i * HID + 32 + slot * 8)     = so;   // s -> h row [32..63]
        }
    }
}

// ==== k_l2g: out[i] = mean_j g[j] + s[i] — DUAL-node gather from dense gbuf ====
__global__ __launch_bounds__(256, 8) void k_l2g(
        const ush* __restrict__ gbuf, const ush* __restrict__ hs,
        const int* __restrict__ cnt, const int* __restrict__ csr,
        const int* __restrict__ ovf, const int* __restrict__ ovfn,
        const int* __restrict__ flags,
        void* __restrict__ out, int n_nodes) {
    int fb = flags[0];
    int t = threadIdx.x;
    int wave = t >> 6, lane = t & 63;
    int slot = lane >> 2;    // 0..15
    int chunk = lane & 3;    // 0..3
    int st = gridDim.x * 4 * 2;
    int i = (blockIdx.x * 4 + wave) * 2;
    if (i >= n_nodes) return;
    int idxv = csr[(size_t)i * S_CAP + lane];
    int dgv  = cnt[min(i + (lane & 1), n_nodes - 1)];
    while (i < n_nodes) {
        int inext = i + st;
        int idxv_n = 0, dgv_n = 0;
        if (inext < n_nodes) {
            idxv_n = csr[(size_t)inext * S_CAP + lane];
            dgv_n  = cnt[min(inext + (lane & 1), n_nodes - 1)];
        }
        int dg0 = __shfl(dgv, 0);
        int dg1 = __shfl(dgv, 1);
        bool has1 = (i + 1) < n_nodes;
        int lim0 = min(dg0, S_CAP);
        int lim1 = has1 ? min(dg1, S_CAP) : 0;
        int lmax = max(lim0, lim1);
        float acc0[8] = {0, 0, 0, 0, 0, 0, 0, 0};
        float acc1[8] = {0, 0, 0, 0, 0, 0, 0, 0};
        for (int g = 0; g < lmax; g += 16) {
            int k = g + slot;
            int s0 = __shfl(idxv, k);
            int s1 = __shfl(idxv, 32 + k);
            bool ok0 = k < lim0;
            bool ok1 = k < lim1;
            ush8 v0 = *(const ush8*)(gbuf + (size_t)(ok0 ? s0 : i) * OUT_CH + chunk * 8);
            ush8 v1 = *(const ush8*)(gbuf + (size_t)(ok1 ? s1 : i) * OUT_CH + chunk * 8);
#pragma unroll
            for (int j = 0; j < 8; ++j) {
                acc0[j] += ok0 ? bf2f(v0[j]) : 0.0f;
                acc1[j] += ok1 ? bf2f(v1[j]) : 0.0f;
            }
        }
        if (dg0 > S_CAP) {   // wave-uniform; ~never taken
            int on = min(*ovfn, OVF_CAP);
            for (int k = 0; k < on; ++k) {
                int2 pr = ((const int2*)ovf)[k];
                if (pr.x == i && slot == 0) {
                    ush8 v = *(const ush8*)(gbuf + (size_t)pr.y * OUT_CH + chunk * 8);
#pragma unroll
                    for (int j = 0; j < 8; ++j) acc0[j] += bf2f(v[j]);
                }
            }
        }
        if (has1 && dg1 > S_CAP) {
            int on = min(*ovfn, OVF_CAP);
            for (int k = 0; k < on; ++k) {
                int2 pr = ((const int2*)ovf)[k];
                if (pr.x == i + 1 && slot == 0) {
                    ush8 v = *(const ush8*)(gbuf + (size_t)pr.y * OUT_CH + chunk * 8);
#pragma unroll
                    for (int j = 0; j < 8; ++j) acc1[j] += bf2f(v[j]);
                }
            }
        }
#pragma unroll
        for (int j = 0; j < 8; ++j) {
            acc0[j] += __shfl_xor(acc0[j], 4);
            acc0[j] += __shfl_xor(acc0[j], 8);
            acc0[j] += __shfl_xor(acc0[j], 16);
            acc0[j] += __shfl_xor(acc0[j], 32);
            acc1[j] += __shfl_xor(acc1[j], 4);
            acc1[j] += __shfl_xor(acc1[j], 8);
            acc1[j] += __shfl_xor(acc1[j], 16);
            acc1[j] += __shfl_xor(acc1[j], 32);
        }
        if (lane < 8) {   // lanes 0..3: node i; lanes 4..7: node i+1
            bool second = lane >= 4;
            if (!second || has1) {
                int node = second ? i + 1 : i;
                int dg = second ? dg1 : dg0;
                float rd = 1.0f / (float)(dg > 1 ? dg : 1);
                int c = lane & 3;
                ush8 selfv = *(const ush8*)(hs + (size_t)node * HID + 32 + c * 8);
                if (fb) {
                    ush8 ov;
#pragma unroll
                    for (int j = 0; j < 8; ++j) {
                        float a = second ? acc1[j] : acc0[j];
                        ov[j] = f2bf(a * rd + bf2f(selfv[j]));
                    }
                    *(ush8*)((ush*)out + (size_t)node * OUT_CH + c * 8) = ov;
                } else {
                    float* op = (float*)out + (size_t)node * OUT_CH + c * 8;
                    f4 a0, a1;
#pragma unroll
                    for (int j = 0; j < 4; ++j) {
                        float x0 = second ? acc1[j]     : acc0[j];
                        float x1 = second ? acc1[4 + j] : acc0[4 + j];
                        a0[j] = x0 * rd + bf2f(selfv[j]);
                        a1[j] = x1 * rd + bf2f(selfv[4 + j]);
                    }
                    *(f4*)op = a0;
                    *(f4*)(op + 4) = a1;
                }
            }
        }
        i = inext; idxv = idxv_n; dgv = dgv_n;
    }
}

extern "C" void kernel_launch(void* const* d_in, const int* in_sizes, int n_in,
                              void* d_out, int out_size, void* d_ws, size_t ws_size,
                              hipStream_t stream) {
    const void* x   = d_in[0];
    const int*  ei  = (const int*)d_in[1];
    const void* W1l = d_in[2];
    const void* W1r = d_in[3];
    const void* b1  = d_in[4];
    const void* W2l = d_in[5];
    const void* W2r = d_in[6];
    const void* b2  = d_in[7];

    int n_nodes = in_sizes[0] / IN_CH;
    int n_edges = in_sizes[1] / 2;

    // ws layout:
    //   [0,256)   flags (2 ints) + ovfn counter (at +128)
    //   cnt (N ints) | csr (N*S_CAP + 64 ints)
    //   | ovf region (OVF_CAP pairs = 640KB), then hist/base/cursor carve:
    //     3*(NB_MAX+2) ints (hist NB_MAX | base NB_MAX+1 | curs NB_MAX)
    //   | h (N*HID bf16)   -- pairs[] for bucketed partition ALIASES h (dead until k_mm1)
    //   | gbuf (N*OUT_CH bf16)
    //   | agg (N*IN_CH f32)  -- only if ws_size permits; else bf16 aliased onto gbuf
    char* ws = (char*)d_ws;
    size_t o_cnt = 256;
    size_t o_csr = (o_cnt + (size_t)n_nodes * 4 + 127) & ~(size_t)127;
    size_t o_ovf = (o_csr + ((size_t)n_nodes * S_CAP + 64) * 4 + 127) & ~(size_t)127;
    size_t o_hist = o_ovf + (size_t)OVF_CAP * 8;
    size_t o_h   = (o_hist + (size_t)(3 * (NB_MAX + 2)) * 4 + 255) & ~(size_t)255;
    size_t o_gb  = (o_h + (size_t)n_nodes * HID * 2 + 255) & ~(size_t)255;
    size_t o_ag  = (o_gb + (size_t)n_nodes * OUT_CH * 2 + 255) & ~(size_t)255;
    size_t need_f32 = o_ag + (size_t)n_nodes * IN_CH * 4;

    int* flags = (int*)ws;
    int* ovfn  = (int*)(ws + 128);
    int* cnt   = (int*)(ws + o_cnt);
    int* csr   = (int*)(ws + o_csr);
    int* ovf   = (int*)(ws + o_ovf);
    int* hist  = (int*)(ws + o_hist);              // NB_MAX ints
    int* base  = hist + NB_MAX;                    // NB_MAX+1 ints
    int* curs  = base + NB_MAX + 1;                // NB_MAX ints
    ush* h     = (ush*)(ws + o_h);
    int* pairs = (int*)(ws + o_h);                 // aliases h; dead before k_mm1
    ush* gbuf  = (ush*)(ws + o_gb);

    int aggf32 = (ws_size >= need_f32) ? 1 : 0;
    float* aggf = (float*)(ws + o_ag);   // valid only if aggf32
    ush*   aggb = gbuf;                  // bf16 fallback aliases gbuf (safe: dead by k_g)

    int NB = (n_nodes + 255) >> 8;       // 256 nodes per bucket
    // bucketed path requires: NB fits LDS; src fits 24 bits; pairs fits in h region
    int use_bucket = (NB <= NB_MAX) && (n_nodes < (1 << 24)) &&
                     ((size_t)n_edges * 4 <= (size_t)n_nodes * HID * 2) && (n_edges > 0);

    hipMemsetAsync(ws, 0, 256, stream);                          // flags + ovfn

    k_detect<<<1, 256, 0, stream>>>((const unsigned short*)x, ei, flags);

    if (use_bucket) {
        hipMemsetAsync(hist, 0, (size_t)NB * 4, stream);
        int nchunks = (n_edges + SC_CHUNK - 1) / SC_CHUNK;
        k_hist<<<256, 256, 0, stream>>>(ei, n_edges, flags, hist, NB);
        k_scan<<<1, 256, 0, stream>>>(hist, base, curs, NB);
        k_scatter<<<nchunks, 256, 0, stream>>>(ei, n_edges, flags, curs, pairs, NB);
        k_build<<<NB, 256, 0, stream>>>(pairs, base, cnt, csr, ovf, ovfn, n_nodes);
    } else {
        hipMemsetAsync(cnt, 0, (size_t)n_nodes * 4, stream);
        k_fillp<<<(n_edges + 255) / 256, 256, 0, stream>>>(ei, n_edges, flags, cnt, csr, ovf, ovfn);
    }

    // gather kernels: lean VGPR (<=64) -> 32 waves/CU; 2048 blocks = 8/CU residency cap
    k_agg1<<<2048, 256, 0, stream>>>(x, cnt, csr, ovf, ovfn, flags, aggf, aggb, aggf32, n_nodes);
    // dense kernels: ~104 VGPR -> 4 blocks/CU cap; 1024 blocks exactly fills it
    k_mm1<<<1024, 256, 0, stream>>>(x, aggf, aggb, aggf32, W1l, W1r, b1, flags, h, n_nodes);
    k_g<<<1024, 256, 0, stream>>>(h, gbuf, W2l, W2r, b2, flags, n_nodes);
    k_l2g<<<2048, 256, 0, stream>>>(gbuf, h, cnt, csr, ovf, ovfn, flags, d_out, n_nodes);
}